// Round 3
// baseline (104.522 us; speedup 1.0000x reference)
//
#include <hip/hip_runtime.h>

// Problem: B=16, S=2048, D=64, fp32.
// out[b] = V[b] @ (K[b]^T @ Q[b])   -- avoids the SxS intermediate.
//
// R3 (= R2 intent, compile-fixed): nontemporal builtins need native clang
// vectors, not HIP_vector_type. Use ext_vector_type(4) float throughout.

typedef float vf4 __attribute__((ext_vector_type(4)));
typedef float vf2 __attribute__((ext_vector_type(2)));

#define BATCH 16
#define SEQ   2048
#define DIM   64
#define SCHUNK 128          // seq rows per block in kernel A
#define NCHUNK (SEQ / SCHUNK)
#define RBLK  64            // V rows per block in kernel B
#define TPAD  68            // transposed-V LDS row stride (floats); 68*4B = 272B = 17*16B -> 16B aligned

// ---------------- Kernel A: M[b] += K_chunk^T @ Q_chunk (atomic) -------------
// 512 threads, 2x4 register tile each: thread (ty,tx) owns M[ty*2..+1][tx*4..+3]
__global__ __launch_bounds__(512) void ktq_kernel(const float* __restrict__ K,
                                                  const float* __restrict__ Q,
                                                  float* __restrict__ M) {
    __shared__ float Ks[SCHUNK * DIM];   // 32 KB
    __shared__ float Qs[SCHUNK * DIM];   // 32 KB
    const int b     = blockIdx.y;
    const int chunk = blockIdx.x;
    const int t     = threadIdx.x;

    const float* Kb = K + (size_t)b * SEQ * DIM + (size_t)chunk * SCHUNK * DIM;
    const float* Qb = Q + (size_t)b * SEQ * DIM + (size_t)chunk * SCHUNK * DIM;

    // Stage: SCHUNK*DIM = 8192 floats = 2048 vf4; 512 threads -> 4 each.
#pragma unroll
    for (int i = 0; i < 4; ++i) {
        int idx = i * 512 + t;
        ((vf4*)Ks)[idx] = __builtin_nontemporal_load(&((const vf4*)Kb)[idx]);
        ((vf4*)Qs)[idx] = __builtin_nontemporal_load(&((const vf4*)Qb)[idx]);
    }
    __syncthreads();

    const int tx = t & 15;   // -> d  (Q) columns  tx*4 .. tx*4+3
    const int ty = t >> 4;   // -> d' (K) rows     ty*2 .. ty*2+1  (0..31)
    float acc[2][4];
#pragma unroll
    for (int i = 0; i < 2; ++i)
#pragma unroll
        for (int j = 0; j < 4; ++j) acc[i][j] = 0.f;

    for (int s = 0; s < SCHUNK; ++s) {
        vf2 ak = *(const vf2*)&Ks[s * DIM + ty * 2];  // few distinct addrs, broadcast-ish
        vf4 bq = *(const vf4*)&Qs[s * DIM + tx * 4];  // 16 distinct b128, 2-way max (free)
#pragma unroll
        for (int i = 0; i < 2; ++i)
#pragma unroll
            for (int j = 0; j < 4; ++j) acc[i][j] += ak[i] * bq[j];
    }

    float* Mb = M + b * DIM * DIM;
#pragma unroll
    for (int i = 0; i < 2; ++i)
#pragma unroll
        for (int j = 0; j < 4; ++j)
            atomicAdd(&Mb[(ty * 2 + i) * DIM + tx * 4 + j], acc[i][j]);
}

// ---------------- Kernel B: out_rows = V_rows @ M[b] -------------------------
__global__ __launch_bounds__(256) void vm_kernel(const float* __restrict__ V,
                                                 const float* __restrict__ M,
                                                 float* __restrict__ O) {
    __shared__ float Ml[DIM * DIM];       // 16 KB, M[d'][d]
    __shared__ float VsT[DIM * TPAD];     // 17 KB, transposed: VsT[dp][row]
    const int b  = blockIdx.y;
    const int rb = blockIdx.x;
    const int t  = threadIdx.x;

    const float* Mb = M + b * DIM * DIM;
    const float* Vb = V + (size_t)b * SEQ * DIM + (size_t)rb * RBLK * DIM;

    // Stage M: 4096 floats = 1024 vf4; 4 per thread.
#pragma unroll
    for (int i = 0; i < 4; ++i) {
        int idx = i * 256 + t;
        ((vf4*)Ml)[idx] = ((const vf4*)Mb)[idx];
    }
    // Stage V transposed: logical V[row][col], stored VsT[col][row].
    // Coalesced vf4 global load; 4 scalar LDS writes (one-time, small).
#pragma unroll
    for (int i = 0; i < 4; ++i) {
        int idx = i * 256 + t;        // vf4 index in [64 rows][16 col-groups]
        int row = idx >> 4;
        int col = (idx & 15) * 4;
        vf4 v = __builtin_nontemporal_load(&((const vf4*)Vb)[idx]);
        VsT[(col + 0) * TPAD + row] = v[0];
        VsT[(col + 1) * TPAD + row] = v[1];
        VsT[(col + 2) * TPAD + row] = v[2];
        VsT[(col + 3) * TPAD + row] = v[3];
    }
    __syncthreads();

    const int tx = t & 15;   // output cols  d  = tx*4 .. +3
    const int ty = t >> 4;   // output rows  v  = ty*4 .. +3 (of this 64-row block)
    float acc[4][4];
#pragma unroll
    for (int i = 0; i < 4; ++i)
#pragma unroll
        for (int j = 0; j < 4; ++j) acc[i][j] = 0.f;

    for (int dp = 0; dp < DIM; ++dp) {
        vf4 mv = *(const vf4*)&Ml[dp * DIM + tx * 4];    // 16 distinct b128
        vf4 av = *(const vf4*)&VsT[dp * TPAD + ty * 4];  // 4 distinct b128, broadcast-ish
#pragma unroll
        for (int i = 0; i < 4; ++i)
#pragma unroll
            for (int j = 0; j < 4; ++j) acc[i][j] += av[i] * mv[j];
    }

    float* Ob = O + (size_t)b * SEQ * DIM + (size_t)rb * RBLK * DIM;
#pragma unroll
    for (int i = 0; i < 4; ++i) {
        vf4 o = {acc[i][0], acc[i][1], acc[i][2], acc[i][3]};
        __builtin_nontemporal_store(o, (vf4*)&Ob[(ty * 4 + i) * DIM + tx * 4]);
    }
}

extern "C" void kernel_launch(void* const* d_in, const int* in_sizes, int n_in,
                              void* d_out, int out_size, void* d_ws, size_t ws_size,
                              hipStream_t stream) {
    const float* Q = (const float*)d_in[0];
    const float* K = (const float*)d_in[1];
    const float* V = (const float*)d_in[2];
    float* O = (float*)d_out;
    float* M = (float*)d_ws;   // BATCH * 64 * 64 floats = 256 KB

    // Workspace is poisoned to 0xAA before every call -> zero the M region.
    (void)hipMemsetAsync(M, 0, (size_t)BATCH * DIM * DIM * sizeof(float), stream);

    dim3 gridA(NCHUNK, BATCH);       // 16 x 16 = 256 blocks, 512 threads
    ktq_kernel<<<gridA, 512, 0, stream>>>(K, Q, M);

    dim3 gridB(SEQ / RBLK, BATCH);   // 32 x 16 = 512 blocks
    vm_kernel<<<gridB, 256, 0, stream>>>(V, M, O);
}